// Round 10
// baseline (201.910 us; speedup 1.0000x reference)
//
#include <hip/hip_runtime.h>
#include <stdint.h>

#define NA   16000
#define KNN  10
#define NRES 400
#define APR  40
#define NCAT 12
#define BERT 1024
#define FF   128
#define DF1  256
#define DF2  64

using short8   = __attribute__((ext_vector_type(8))) short;
using floatx4  = __attribute__((ext_vector_type(4))) float;
using ushort8v = __attribute__((ext_vector_type(8))) unsigned short;

__device__ __forceinline__ unsigned short bfc(float v) {
    return __builtin_bit_cast(unsigned short, (__bf16)v);
}
__device__ __forceinline__ float bflo(uint32_t u){ return __uint_as_float(u << 16); }
__device__ __forceinline__ float bfhi(uint32_t u){ return __uint_as_float(u & 0xffff0000u); }

// ---------------------------------------------------------------------------
// Weight prep: plain transposes to bf16, n-major (no swizzle — GEMMs are
// barrier/LDS-free and read fragments directly from global).
// WrT [128][1024], Bt3 [3][128][128], W2T [64][256].
// ---------------------------------------------------------------------------
__global__ void k_prep(const float* __restrict__ Wr,
                       const float* __restrict__ Wsv, const float* __restrict__ Wsr2,
                       const float* __restrict__ Wdr2, const float* __restrict__ Wf2,
                       unsigned short* __restrict__ WrT, unsigned short* __restrict__ Bt3,
                       unsigned short* __restrict__ W2T)
{
    int idx = blockIdx.x * 256 + threadIdx.x;
    if (idx < FF * BERT) {                              // WrT[n][k]
        int n = idx >> 10, k = idx & 1023;
        WrT[idx] = bfc(Wr[(size_t)k * FF + n]);
    } else if (idx < FF * BERT + 3 * FF * FF) {         // Bt3[m][n][k]
        int i2 = idx - FF * BERT;
        int m = i2 >> 14, r2 = i2 & 16383;
        int n = r2 >> 7, k = r2 & 127;
        const float* W = (m == 0) ? Wsv : ((m == 1) ? Wsr2 : Wdr2);
        Bt3[i2] = bfc(W[(size_t)k * FF + n]);
    } else {                                            // W2T[n][k]
        int i3 = idx - FF * BERT - 3 * FF * FF;
        int n = i3 >> 8, k = i3 & 255;
        W2T[i3] = bfc(Wf2[(size_t)k * DF2 + n]);
    }
}

// ---------------------------------------------------------------------------
// SD[a][0:128]=bf16(atoms@Wsr1), [128:256]=bf16(atoms@Wdr1).
// ---------------------------------------------------------------------------
__global__ void __launch_bounds__(256)
k_atomsSD(const float* __restrict__ atoms0, const float* __restrict__ atoms1,
          const float* __restrict__ Wsr1, const float* __restrict__ Wdr1,
          unsigned short* __restrict__ SD)
{
    __shared__ float sAt[64 * NCAT];   // 3 KB
    const int p = blockIdx.y;
    const float* atoms = p ? atoms1 : atoms0;
    unsigned short* SDp = SD + (size_t)p * 4096000;
    const int a0 = blockIdx.x * 64;
    const int tid = threadIdx.x;
    const int f = tid & 127, half = tid >> 7;

    if (tid < 192)
        ((float4*)sAt)[tid] = *(const float4*)&atoms[(size_t)a0 * NCAT + tid * 4];

    float wsr[NCAT], wdr[NCAT];
#pragma unroll
    for (int c = 0; c < NCAT; ++c) {
        wsr[c] = Wsr1[c * FF + f];
        wdr[c] = Wdr1[c * FF + f];
    }
    __syncthreads();

#pragma unroll 4
    for (int pass = 0; pass < 32; ++pass) {
        int ai = pass * 2 + half;
        int a = a0 + ai;
        float ss = 0.f, sd = 0.f;
#pragma unroll
        for (int c = 0; c < NCAT; ++c) {
            float ac = sAt[ai * NCAT + c];
            ss = fmaf(ac, wsr[c], ss);
            sd = fmaf(ac, wdr[c], sd);
        }
        SDp[(size_t)a * 256 + f]       = bfc(ss);
        SDp[(size_t)a * 256 + 128 + f] = bfc(sd);
    }
}

// ---------------------------------------------------------------------------
// Big GEMM, barrier-free streaming: residues[16000,1024] @ Wr.
// Each wave owns a 16-row m-tile; A-frag (32B/lane fp32->bf16) and B-frags
// (16B/lane from L2-resident WrT[n][k]) are loaded per-lane directly from
// global in exactly the MFMA fragment layout (row=l&15, k=(l>>4)*8+e).
// Split-K x2 for TLP: chunk0 -> ACC, chunk1 -> P1 (summed in k_gather1).
// blockIdx: x = m-block (4 waves x 16 rows), y = k-chunk, z = protein.
// ---------------------------------------------------------------------------
__global__ void __launch_bounds__(256)
k_gemm_big(const float* __restrict__ R0, const float* __restrict__ R1,
           const unsigned short* __restrict__ Bt,
           float* __restrict__ ACC, float* __restrict__ P1)
{
    const int tid = threadIdx.x, l = tid & 63, w = tid >> 6;
    const int m0 = blockIdx.x * 64 + w * 16;
    const int kc = blockIdx.y;
    const float* A = blockIdx.z ? R1 : R0;
    float* C = ((kc == 0) ? ACC : P1) + (size_t)blockIdx.z * 2048000;
    const int lr = l & 15, lq = l >> 4;

    const float*          ap = A  + (size_t)(m0 + lr) * BERT + kc * 512 + lq * 8;
    const unsigned short* bp = Bt + (size_t)lr * BERT        + kc * 512 + lq * 8;

    floatx4 acc[8];
#pragma unroll
    for (int nt = 0; nt < 8; ++nt) acc[nt] = (floatx4){0.f, 0.f, 0.f, 0.f};

#pragma unroll 4
    for (int kt = 0; kt < 16; ++kt) {
        float4 a0 = *(const float4*)(ap + kt * 32);
        float4 a1 = *(const float4*)(ap + kt * 32 + 4);
        short8 af;
        af[0] = (short)bfc(a0.x); af[1] = (short)bfc(a0.y);
        af[2] = (short)bfc(a0.z); af[3] = (short)bfc(a0.w);
        af[4] = (short)bfc(a1.x); af[5] = (short)bfc(a1.y);
        af[6] = (short)bfc(a1.z); af[7] = (short)bfc(a1.w);
#pragma unroll
        for (int nt = 0; nt < 8; ++nt) {
            short8 bf = *(const short8*)(bp + (size_t)nt * 16 * BERT + kt * 32);
            acc[nt] = __builtin_amdgcn_mfma_f32_16x16x32_bf16(af, bf, acc[nt], 0, 0, 0);
        }
    }

#pragma unroll
    for (int nt = 0; nt < 8; ++nt)
#pragma unroll
        for (int r = 0; r < 4; ++r)
            C[(size_t)(m0 + lq * 4 + r) * FF + nt * 16 + lr] = acc[nt][r];
}

// ---------------------------------------------------------------------------
// Layer-2 GEMM, barrier-free streaming: Z[16000,128]bf16 @ {Wsv,Wsr2,Wdr2}.
// blockIdx: x = m-block, y = mat, z = protein.  K=128 (4 steps).
// ---------------------------------------------------------------------------
__global__ void __launch_bounds__(256)
k_gemm_l2(const unsigned short* __restrict__ Z, const unsigned short* __restrict__ Bt3,
          float* __restrict__ ACC, unsigned short* __restrict__ SD)
{
    const int tid = threadIdx.x, l = tid & 63, w = tid >> 6;
    const int m0 = blockIdx.x * 64 + w * 16;
    const int mat = blockIdx.y, p = blockIdx.z;
    const int lr = l & 15, lq = l >> 4;

    const unsigned short* ap = Z + (size_t)p * 2048000 + (size_t)(m0 + lr) * FF + lq * 8;
    const unsigned short* bp = Bt3 + (size_t)mat * 16384 + (size_t)lr * FF + lq * 8;

    floatx4 acc[8];
#pragma unroll
    for (int nt = 0; nt < 8; ++nt) acc[nt] = (floatx4){0.f, 0.f, 0.f, 0.f};

#pragma unroll
    for (int kt = 0; kt < 4; ++kt) {
        short8 af = *(const short8*)(ap + kt * 32);
#pragma unroll
        for (int nt = 0; nt < 8; ++nt) {
            short8 bf = *(const short8*)(bp + (size_t)nt * 16 * FF + kt * 32);
            acc[nt] = __builtin_amdgcn_mfma_f32_16x16x32_bf16(af, bf, acc[nt], 0, 0, 0);
        }
    }

    float* ACCp = ACC + (size_t)p * 2048000;
    unsigned short* SDp = SD + (size_t)p * 4096000;
#pragma unroll
    for (int nt = 0; nt < 8; ++nt)
#pragma unroll
        for (int r = 0; r < 4; ++r) {
            int row = m0 + lq * 4 + r;
            int col = nt * 16 + lr;
            float v = acc[nt][r];
            if (mat == 0) ACCp[(size_t)row * FF + col] = v;
            else          SDp [(size_t)row * 256 + (mat - 1) * FF + col] = bfc(v);
        }
}

// ---------------------------------------------------------------------------
// Gather 1: Z = relu(ACC + P1 + atoms@Wv + mean(S,sn) + mean(D,dn)) -> Z
// (linear bf16 [a][128] — feeds the streaming k_gemm_l2 directly).
// ---------------------------------------------------------------------------
__global__ void __launch_bounds__(256)
k_gather1(const float* __restrict__ ACC, const float* __restrict__ P1,
          const unsigned short* __restrict__ SD,
          const int* __restrict__ sn0, const int* __restrict__ dn0,
          const int* __restrict__ sn1, const int* __restrict__ dn1,
          const float* __restrict__ atoms0, const float* __restrict__ atoms1,
          const float* __restrict__ Wv, unsigned short* __restrict__ Zout)
{
    __shared__ int sIdx[16][20];
    __shared__ float sWv[NCAT * FF];   // 6 KB
    __shared__ float sAt[16 * NCAT];   // 768 B
    const int tid = threadIdx.x;
    const int p = blockIdx.y;
    const int a0 = blockIdx.x * 16;
    const int* sn = p ? sn1 : sn0;
    const int* dn = p ? dn1 : dn0;
    const float* ACCp = ACC + (size_t)p * 2048000;
    const float* P1p  = P1  + (size_t)p * 2048000;
    const unsigned short* SDp = SD + (size_t)p * 4096000;
    unsigned short* Zp = Zout + (size_t)p * 2048000;

    for (int t = tid; t < 320; t += 256) {
        int at = t / 20, q = t - at * 20;
        sIdx[at][q] = (q < 10) ? sn[(a0 + at) * KNN + q] : dn[(a0 + at) * KNN + q - 10];
    }
    {
        const float* atoms = p ? atoms1 : atoms0;
        for (int i = tid; i < 384; i += 256)
            ((float4*)sWv)[i] = ((const float4*)Wv)[i];
        if (tid < 48) {
            int at = tid / 3, q = tid - at * 3;
            *(float4*)&sAt[at * NCAT + q * 4] =
                *(const float4*)&atoms[(size_t)(a0 + at) * NCAT + q * 4];
        }
    }
    __syncthreads();
    const int at = tid >> 4, c8 = tid & 15;
    const int a = a0 + at;
    float ss[8] = {0,0,0,0,0,0,0,0}, dd[8] = {0,0,0,0,0,0,0,0};
    int sc = 0, dc = 0;
#pragma unroll
    for (int n = 0; n < KNN; ++n) {
        int is = sIdx[at][n];
        if (is > -1) {
            sc++;
            uint4 v = *(const uint4*)&SDp[(size_t)is * 256 + c8 * 8];
            uint32_t vv[4] = {v.x, v.y, v.z, v.w};
#pragma unroll
            for (int q = 0; q < 4; ++q) { ss[2*q] += bflo(vv[q]); ss[2*q+1] += bfhi(vv[q]); }
        }
    }
#pragma unroll
    for (int n = 0; n < KNN; ++n) {
        int id = sIdx[at][10 + n];
        if (id > -1) {
            dc++;
            uint4 v = *(const uint4*)&SDp[(size_t)id * 256 + 128 + c8 * 8];
            uint32_t vv[4] = {v.x, v.y, v.z, v.w};
#pragma unroll
            for (int q = 0; q < 4; ++q) { dd[2*q] += bflo(vv[q]); dd[2*q+1] += bfhi(vv[q]); }
        }
    }
    const float rs = 1.f / (sc > 0 ? (float)sc : 1.f);
    const float rd = 1.f / (dc > 0 ? (float)dc : 1.f);
    float4 a0v = *(const float4*)&ACCp[(size_t)a * FF + c8 * 8];
    float4 a1v = *(const float4*)&ACCp[(size_t)a * FF + c8 * 8 + 4];
    float4 p0v = *(const float4*)&P1p[(size_t)a * FF + c8 * 8];
    float4 p1v = *(const float4*)&P1p[(size_t)a * FF + c8 * 8 + 4];
    float ov[8] = {a0v.x + p0v.x, a0v.y + p0v.y, a0v.z + p0v.z, a0v.w + p0v.w,
                   a1v.x + p1v.x, a1v.y + p1v.y, a1v.z + p1v.z, a1v.w + p1v.w};
#pragma unroll
    for (int c = 0; c < NCAT; ++c) {
        float ac = sAt[at * NCAT + c];
        float4 w0 = *(const float4*)&sWv[c * FF + c8 * 8];
        float4 w1 = *(const float4*)&sWv[c * FF + c8 * 8 + 4];
        ov[0] = fmaf(ac, w0.x, ov[0]); ov[1] = fmaf(ac, w0.y, ov[1]);
        ov[2] = fmaf(ac, w0.z, ov[2]); ov[3] = fmaf(ac, w0.w, ov[3]);
        ov[4] = fmaf(ac, w1.x, ov[4]); ov[5] = fmaf(ac, w1.y, ov[5]);
        ov[6] = fmaf(ac, w1.z, ov[6]); ov[7] = fmaf(ac, w1.w, ov[7]);
    }
    ushort8v zv;
#pragma unroll
    for (int e = 0; e < 8; ++e)
        zv[e] = bfc(fmaxf(fmaf(ss[e], rs, fmaf(dd[e], rd, ov[e])), 0.f));
    *(ushort8v*)(Zp + (size_t)a * FF + c8 * 8) = zv;
}

// ---------------------------------------------------------------------------
// Gather 2 fused with residue mean: one block per residue (40 atoms).
// ---------------------------------------------------------------------------
__global__ void __launch_bounds__(256)
k_gather_res(const float* __restrict__ ACC, const unsigned short* __restrict__ SD,
             const int* __restrict__ sn0, const int* __restrict__ dn0,
             const int* __restrict__ sn1, const int* __restrict__ dn1,
             float* __restrict__ R12)
{
    __shared__ int sIdx[APR][20];      // 3.2 KB
    __shared__ float zpart[16][128];   // 8 KB
    const int tid = threadIdx.x;
    const int p = blockIdx.y, r = blockIdx.x;
    const int* sn = p ? sn1 : sn0;
    const int* dn = p ? dn1 : dn0;
    const float* ACCp = ACC + (size_t)p * 2048000;
    const unsigned short* SDp = SD + (size_t)p * 4096000;
    const int aBase = r * APR;

    for (int t = tid; t < APR * 20; t += 256) {
        int at = t / 20, q = t - at * 20;
        sIdx[at][q] = (q < 10) ? sn[(aBase + at) * KNN + q] : dn[(aBase + at) * KNN + q - 10];
    }
    __syncthreads();

    const int at = tid >> 4, c8 = tid & 15;
    float zs[8] = {0,0,0,0,0,0,0,0};
#pragma unroll
    for (int rep = 0; rep < 3; ++rep) {
        int ai = at + rep * 16;
        if (ai < APR) {
            int a = aBase + ai;
            float ss[8] = {0,0,0,0,0,0,0,0}, dd[8] = {0,0,0,0,0,0,0,0};
            int sc = 0, dc = 0;
#pragma unroll
            for (int n = 0; n < KNN; ++n) {
                int is = sIdx[ai][n];
                if (is > -1) {
                    sc++;
                    uint4 v = *(const uint4*)&SDp[(size_t)is * 256 + c8 * 8];
                    uint32_t vv[4] = {v.x, v.y, v.z, v.w};
#pragma unroll
                    for (int q = 0; q < 4; ++q) { ss[2*q] += bflo(vv[q]); ss[2*q+1] += bfhi(vv[q]); }
                }
            }
#pragma unroll
            for (int n = 0; n < KNN; ++n) {
                int id = sIdx[ai][10 + n];
                if (id > -1) {
                    dc++;
                    uint4 v = *(const uint4*)&SDp[(size_t)id * 256 + 128 + c8 * 8];
                    uint32_t vv[4] = {v.x, v.y, v.z, v.w};
#pragma unroll
                    for (int q = 0; q < 4; ++q) { dd[2*q] += bflo(vv[q]); dd[2*q+1] += bfhi(vv[q]); }
                }
            }
            const float rs = 1.f / (sc > 0 ? (float)sc : 1.f);
            const float rd = 1.f / (dc > 0 ? (float)dc : 1.f);
            float4 a0v = *(const float4*)&ACCp[(size_t)a * FF + c8 * 8];
            float4 a1v = *(const float4*)&ACCp[(size_t)a * FF + c8 * 8 + 4];
            float ov[8] = {a0v.x, a0v.y, a0v.z, a0v.w, a1v.x, a1v.y, a1v.z, a1v.w};
#pragma unroll
            for (int e = 0; e < 8; ++e)
                zs[e] += fmaxf(fmaf(ss[e], rs, fmaf(dd[e], rd, ov[e])), 0.f);
        }
    }
    *(float4*)&zpart[at][c8 * 8]     = (float4){zs[0], zs[1], zs[2], zs[3]};
    *(float4*)&zpart[at][c8 * 8 + 4] = (float4){zs[4], zs[5], zs[6], zs[7]};
    __syncthreads();
#pragma unroll
    for (int s = 8; s > 0; s >>= 1) {
        if (at < s) {
            float4 x0 = *(const float4*)&zpart[at + s][c8 * 8];
            float4 x1 = *(const float4*)&zpart[at + s][c8 * 8 + 4];
            float4 y0 = *(const float4*)&zpart[at][c8 * 8];
            float4 y1 = *(const float4*)&zpart[at][c8 * 8 + 4];
            y0.x += x0.x; y0.y += x0.y; y0.z += x0.z; y0.w += x0.w;
            y1.x += x1.x; y1.y += x1.y; y1.z += x1.z; y1.w += x1.w;
            *(float4*)&zpart[at][c8 * 8]     = y0;
            *(float4*)&zpart[at][c8 * 8 + 4] = y1;
        }
        __syncthreads();
    }
    if (at == 0) {
        float* R = R12 + (size_t)p * 51200 + (size_t)r * FF;
        const float inv = 1.0f / APR;
#pragma unroll
        for (int e = 0; e < 8; ++e) R[c8 * 8 + e] = zpart[0][c8 * 8 + e] * inv;
    }
}

// ---------------------------------------------------------------------------
// A1[i] = r1[i] @ Wf1[:128,:] + bf1 ;  B1[j] = r2[j] @ Wf1[128:,:]
// ---------------------------------------------------------------------------
__global__ void k_pairprep(const float* __restrict__ R1, const float* __restrict__ R2,
                           const float* __restrict__ Wf1, const float* __restrict__ bf1,
                           float* __restrict__ A1, float* __restrict__ B1)
{
    __shared__ float r1s[FF], r2s[FF];
    int i = blockIdx.x, o = threadIdx.x;   // 256 threads
    if (o < FF) r1s[o] = R1[i * FF + o];
    else        r2s[o - FF] = R2[i * FF + (o - FF)];
    __syncthreads();
    float sa = bf1[o], sb = 0.f;
#pragma unroll 8
    for (int k = 0; k < FF; ++k) {
        sa = fmaf(r1s[k], Wf1[(size_t)k * DF1 + o], sa);
        sb = fmaf(r2s[k], Wf1[(size_t)(FF + k) * DF1 + o], sb);
    }
    A1[(size_t)i * DF1 + o] = sa;
    B1[(size_t)i * DF1 + o] = sb;
}

// ---------------------------------------------------------------------------
// Pair MLP via MFMA, register-built H.
// ---------------------------------------------------------------------------
__global__ void __launch_bounds__(256)
k_pairs_mfma(const float* __restrict__ A1, const float* __restrict__ B1,
             const unsigned short* __restrict__ W2T,
             const float* __restrict__ bf2, const float* __restrict__ Wf3,
             const float* __restrict__ bf3, float* __restrict__ out)
{
    __shared__ __align__(16) float sA1[16 * 256];            // 16 KB linear
    __shared__ __align__(16) float sB1[16 * 256];            // 16 KB, XOR (row&7)<<5
    __shared__ __align__(16) unsigned short sW[64 * 256];    // 32 KB, XOR (n&7)<<4
    const int tid = threadIdx.x, l = tid & 63, w = tid >> 6;
    const int i0 = blockIdx.x * 16, j0 = blockIdx.y * 16;

    for (int idx = tid; idx < 64 * 32; idx += 256) {
        int row = idx >> 5, c = idx & 31;
        int ba = (row * 512 + c * 16) ^ ((row & 7) << 4);
        *(uint4*)((char*)sW + ba) = *(const uint4*)(W2T + row * 256 + c * 8);
    }
    {
        int row = tid >> 4;
#pragma unroll
        for (int pass = 0; pass < 4; ++pass) {
            int coff = pass * 64 + (tid & 15) * 4;
            *(float4*)((char*)sA1 + row * 1024 + coff * 4) =
                *(const float4*)&A1[(size_t)(i0 + row) * DF1 + coff];
            int bb = (row * 1024 + coff * 4) ^ ((row & 7) << 5);
            *(float4*)((char*)sB1 + bb) =
                *(const float4*)&B1[(size_t)(j0 + row) * DF1 + coff];
        }
    }
    __syncthreads();

    floatx4 acc[4][4];
#pragma unroll
    for (int mt = 0; mt < 4; ++mt)
#pragma unroll
        for (int nt = 0; nt < 4; ++nt) acc[mt][nt] = (floatx4){0.f, 0.f, 0.f, 0.f};

    float b2r[4], w3r[4];
#pragma unroll
    for (int nt = 0; nt < 4; ++nt) {
        b2r[nt] = bf2[nt * 16 + (l & 15)];
        w3r[nt] = Wf3[nt * 16 + (l & 15)];
    }

    const int rB = l & 15, kq = l >> 4;
#pragma unroll
    for (int kc = 0; kc < 4; ++kc)
#pragma unroll
        for (int ks = 0; ks < 2; ++ks) {
            const int kfb = (kc * 64 + ks * 32 + kq * 8) * 4;
            float4 b1a = *(const float4*)((char*)sB1 + ((rB * 1024 + kfb)      ^ ((rB & 7) << 5)));
            float4 b1b = *(const float4*)((char*)sB1 + ((rB * 1024 + kfb + 16) ^ ((rB & 7) << 5)));
            short8 afr[4];
#pragma unroll
            for (int mt = 0; mt < 4; ++mt) {
                int rA = w * 4 + mt;
                float4 a1a = *(const float4*)((char*)sA1 + rA * 1024 + kfb);
                float4 a1b = *(const float4*)((char*)sA1 + rA * 1024 + kfb + 16);
                short8 hv;
                hv[0] = (short)bfc(fmaxf(a1a.x + b1a.x, 0.f));
                hv[1] = (short)bfc(fmaxf(a1a.y + b1a.y, 0.f));
                hv[2] = (short)bfc(fmaxf(a1a.z + b1a.z, 0.f));
                hv[3] = (short)bfc(fmaxf(a1a.w + b1a.w, 0.f));
                hv[4] = (short)bfc(fmaxf(a1b.x + b1b.x, 0.f));
                hv[5] = (short)bfc(fmaxf(a1b.y + b1b.y, 0.f));
                hv[6] = (short)bfc(fmaxf(a1b.z + b1b.z, 0.f));
                hv[7] = (short)bfc(fmaxf(a1b.w + b1b.w, 0.f));
                afr[mt] = hv;
            }
            const int kwb = kc * 128 + ks * 64 + kq * 16;
            short8 bfr[4];
#pragma unroll
            for (int nt = 0; nt < 4; ++nt) {
                int n = nt * 16 + (l & 15);
                bfr[nt] = *(const short8*)((char*)sW + ((n * 512 + kwb) ^ ((n & 7) << 4)));
            }
#pragma unroll
            for (int mt = 0; mt < 4; ++mt)
#pragma unroll
                for (int nt = 0; nt < 4; ++nt)
                    acc[mt][nt] = __builtin_amdgcn_mfma_f32_16x16x32_bf16(afr[mt], bfr[nt], acc[mt][nt], 0, 0, 0);
        }

    const float b3 = bf3[0];
#pragma unroll
    for (int mt = 0; mt < 4; ++mt)
#pragma unroll
        for (int r = 0; r < 4; ++r) {
            float s = 0.f;
#pragma unroll
            for (int nt = 0; nt < 4; ++nt)
                s += fmaxf(acc[mt][nt][r] + b2r[nt], 0.f) * w3r[nt];
            s += __shfl_xor(s, 1); s += __shfl_xor(s, 2);
            s += __shfl_xor(s, 4); s += __shfl_xor(s, 8);
            if ((l & 15) == 0) {
                int p = w * 64 + mt * 16 + (l >> 4) * 4 + r;
                out[(size_t)(i0 + (p >> 4)) * NRES + j0 + (p & 15)] = s + b3;
            }
        }
}

// ---------------------------------------------------------------------------
extern "C" void kernel_launch(void* const* d_in, const int* in_sizes, int n_in,
                              void* d_out, int out_size, void* d_ws, size_t ws_size,
                              hipStream_t stream)
{
    const float* atoms0    = (const float*)d_in[0];
    const float* residues0 = (const float*)d_in[1];
    const int*   same0     = (const int*)d_in[2];
    const int*   diff0     = (const int*)d_in[3];
    const float* atoms1    = (const float*)d_in[5];
    const float* residues1 = (const float*)d_in[6];
    const int*   same1     = (const int*)d_in[7];
    const int*   diff1     = (const int*)d_in[8];
    const float* Wv   = (const float*)d_in[10];
    const float* Wr   = (const float*)d_in[11];
    const float* Wsr1 = (const float*)d_in[12];
    const float* Wdr1 = (const float*)d_in[13];
    const float* Wsv  = (const float*)d_in[14];
    const float* Wsr2 = (const float*)d_in[15];
    const float* Wdr2 = (const float*)d_in[16];
    const float* Wf1  = (const float*)d_in[17];
    const float* bf1  = (const float*)d_in[18];
    const float* Wf2  = (const float*)d_in[19];
    const float* bf2  = (const float*)d_in[20];
    const float* Wf3  = (const float*)d_in[21];
    const float* bf3  = (const float*)d_in[22];

    float* ws  = (float*)d_ws;
    float* ACC = ws;                                         // 2 x 2,048,000 f
    float* P1  = ws + 4096000;                               // 2 x 2,048,000 f
    unsigned short* SD = (unsigned short*)(ws + 8192000);    // 2 x 4,096,000 u16
    unsigned short* Z  = (unsigned short*)(ws + 12288000);   // 2 x 2,048,000 u16
    float* R12 = ws + 14336000;                              // 2 x 51,200 f
    float* A1  = ws + 14438400;                              // 102,400 f
    float* B1  = ws + 14540800;                              // 102,400 f
    unsigned short* WrT = (unsigned short*)(ws + 14643200);  // 131,072 u16
    unsigned short* Bt3 = (unsigned short*)(ws + 14708736);  //  49,152 u16
    unsigned short* W2T = (unsigned short*)(ws + 14733312);  //  16,384 u16

    k_prep<<<768, 256, 0, stream>>>(Wr, Wsv, Wsr2, Wdr2, Wf2, WrT, Bt3, W2T);
    k_atomsSD<<<dim3(NA / 64, 2), 256, 0, stream>>>(atoms0, atoms1, Wsr1, Wdr1, SD);
    k_gemm_big<<<dim3(NA / 64, 2, 2), 256, 0, stream>>>(residues0, residues1, WrT, ACC, P1);
    k_gather1<<<dim3(NA / 16, 2), 256, 0, stream>>>(ACC, P1, SD, same0, diff0, same1, diff1,
                                                    atoms0, atoms1, Wv, Z);
    k_gemm_l2<<<dim3(NA / 64, 3, 2), 256, 0, stream>>>(Z, Bt3, ACC, SD);
    k_gather_res<<<dim3(NRES, 2), 256, 0, stream>>>(ACC, SD, same0, diff0, same1, diff1, R12);
    k_pairprep<<<NRES, 256, 0, stream>>>(R12, R12 + 51200, Wf1, bf1, A1, B1);
    k_pairs_mfma<<<dim3(25, 25), 256, 0, stream>>>(A1, B1, W2T, bf2, Wf3, bf3, (float*)d_out);
}

// Round 11
// 133.564 us; speedup vs baseline: 1.5117x; 1.5117x over previous
//
#include <hip/hip_runtime.h>
#include <stdint.h>

#define NA   16000
#define KNN  10
#define NRES 400
#define APR  40
#define NCAT 12
#define BERT 1024
#define FF   128
#define DF1  256
#define DF2  64

using short8   = __attribute__((ext_vector_type(8))) short;
using floatx4  = __attribute__((ext_vector_type(4))) float;
using ushort4v = __attribute__((ext_vector_type(4))) unsigned short;
using ushort8v = __attribute__((ext_vector_type(8))) unsigned short;

__device__ __forceinline__ unsigned short bfc(float v) {
    return __builtin_bit_cast(unsigned short, (__bf16)v);
}
__device__ __forceinline__ float bflo(uint32_t u){ return __uint_as_float(u << 16); }
__device__ __forceinline__ float bfhi(uint32_t u){ return __uint_as_float(u & 0xffff0000u); }

// async global->LDS, 16B per lane
__device__ __forceinline__ void gload16(void* lds, const void* g) {
    __builtin_amdgcn_global_load_lds(
        (const __attribute__((address_space(1))) uint32_t*)g,
        (__attribute__((address_space(3))) uint32_t*)lds, 16, 0, 0);
}

// ---------------------------------------------------------------------------
// Weight prep.
// WrT: 2 k-chunks x swizzled [128 n][512 k] bf16 image (128 KB each) so a
//      LINEAR gload copy into LDS reproduces byte (n*1024+k*2)^((n&7)<<4).
// Bt3: 3 mats x 2 pre-swizzled 128x64 tiles (for k_gemm_l2's gload staging).
// W2T: [64][256] linear bf16.
// ---------------------------------------------------------------------------
__global__ void k_prep(const float* __restrict__ Wr,
                       const float* __restrict__ Wsv, const float* __restrict__ Wsr2,
                       const float* __restrict__ Wdr2, const float* __restrict__ Wf2,
                       unsigned short* __restrict__ WrT, unsigned short* __restrict__ Bt3,
                       unsigned short* __restrict__ W2T)
{
    int idx = blockIdx.x * 256 + threadIdx.x;
    if (idx < 16384) {                       // WrT: 2 chunks x 128 n x 64 kq
        int c = idx >> 13, rem = idx & 8191, n = rem >> 6, kq = rem & 63;
        ushort8v v;
#pragma unroll
        for (int e = 0; e < 8; ++e)
            v[e] = bfc(Wr[(size_t)(c * 512 + kq * 8 + e) * FF + n]);
        int ba = c * 131072 + ((n * 1024 + kq * 16) ^ ((n & 7) << 4));
        *(ushort8v*)((char*)WrT + ba) = v;
    } else if (idx < 16384 + 6144) {         // Bt3: 3 mats x 2 tiles x 128 x 8
        int i2 = idx - 16384;
        int m = i2 >> 11, r2 = i2 & 2047;
        int t = r2 >> 10, r3 = r2 & 1023, n = r3 >> 3, kq = r3 & 7;
        const float* W = (m == 0) ? Wsv : ((m == 1) ? Wsr2 : Wdr2);
        ushort8v v;
#pragma unroll
        for (int e = 0; e < 8; ++e)
            v[e] = bfc(W[(size_t)(t * 64 + kq * 8 + e) * FF + n]);
        int ba = (m * 2 + t) * 16384 + ((n * 128 + kq * 16) ^ ((n & 7) << 4));
        *(ushort8v*)((char*)Bt3 + ba) = v;
    } else {                                 // W2T
        int i3 = idx - 16384 - 6144;
        int n = i3 >> 8, k = i3 & 255;
        W2T[i3] = bfc(Wf2[(size_t)k * DF2 + n]);
    }
}

// ---------------------------------------------------------------------------
// SD[a][0:128]=bf16(atoms@Wsr1), [128:256]=bf16(atoms@Wdr1).
// ---------------------------------------------------------------------------
__global__ void __launch_bounds__(256)
k_atomsSD(const float* __restrict__ atoms0, const float* __restrict__ atoms1,
          const float* __restrict__ Wsr1, const float* __restrict__ Wdr1,
          unsigned short* __restrict__ SD)
{
    __shared__ float sAt[64 * NCAT];   // 3 KB
    const int p = blockIdx.y;
    const float* atoms = p ? atoms1 : atoms0;
    unsigned short* SDp = SD + (size_t)p * 4096000;
    const int a0 = blockIdx.x * 64;
    const int tid = threadIdx.x;
    const int f = tid & 127, half = tid >> 7;

    if (tid < 192)
        ((float4*)sAt)[tid] = *(const float4*)&atoms[(size_t)a0 * NCAT + tid * 4];

    float wsr[NCAT], wdr[NCAT];
#pragma unroll
    for (int c = 0; c < NCAT; ++c) {
        wsr[c] = Wsr1[c * FF + f];
        wdr[c] = Wdr1[c * FF + f];
    }
    __syncthreads();

#pragma unroll 4
    for (int pass = 0; pass < 32; ++pass) {
        int ai = pass * 2 + half;
        int a = a0 + ai;
        float ss = 0.f, sd = 0.f;
#pragma unroll
        for (int c = 0; c < NCAT; ++c) {
            float ac = sAt[ai * NCAT + c];
            ss = fmaf(ac, wsr[c], ss);
            sd = fmaf(ac, wdr[c], sd);
        }
        SDp[(size_t)a * 256 + f]       = bfc(ss);
        SDp[(size_t)a * 256 + 128 + f] = bfc(sd);
    }
}

// ---------------------------------------------------------------------------
// Big GEMM: residues[16000,1024] @ Wr, split-K x2, B-chunk fully LDS-resident.
// 512 threads (8 waves), LDS = 128 KB swizzled B [128n][512k] staged ONCE;
// then ZERO barriers: each wave independently owns one 32-row m-unit,
// streaming A per-lane (coalesced 128B/row) and B via ds_read_b128.
// blockIdx: x in [0,63) (504 waves ~ 500 units), y = k-chunk, z = protein.
// chunk0 -> ACC, chunk1 -> P1 (summed in k_gather1).
// ---------------------------------------------------------------------------
__global__ void __launch_bounds__(512)
k_gemm_big(const float* __restrict__ R0, const float* __restrict__ R1,
           const unsigned short* __restrict__ WrT,
           float* __restrict__ ACC, float* __restrict__ P1)
{
    __shared__ __align__(16) unsigned short sB[65536];   // 128 KB
    const int tid = threadIdx.x, l = tid & 63, w = tid >> 6;
    const int kc = blockIdx.y;
    const float* A = blockIdx.z ? R1 : R0;
    float* C = ((kc == 0) ? ACC : P1) + (size_t)blockIdx.z * 2048000;
    const int lr = l & 15, lq = l >> 4;

    // ---- stage B chunk once (linear copy of pre-swizzled image) ----
    {
        const char* bs = (const char*)WrT + (size_t)kc * 131072 + tid * 16;
        char* bd = (char*)sB + tid * 16;
#pragma unroll
        for (int q = 0; q < 16; ++q) gload16(bd + q * 8192, bs + q * 8192);
    }
    __syncthreads();   // only barrier in the kernel

    const int g = blockIdx.x * 8 + w;       // wave id in [0,504)
    if (g >= 500) return;
    const int m0 = g * 32;

    const float* ap0 = A + (size_t)(m0 + lr) * BERT + kc * 512 + lq * 8;
    const float* ap1 = ap0 + (size_t)16 * BERT;

    floatx4 acc[2][8];
#pragma unroll
    for (int s = 0; s < 2; ++s)
#pragma unroll
        for (int nt = 0; nt < 8; ++nt) acc[s][nt] = (floatx4){0.f, 0.f, 0.f, 0.f};

#pragma unroll 4
    for (int kt = 0; kt < 16; ++kt) {
        float4 a00 = *(const float4*)(ap0 + kt * 32);
        float4 a01 = *(const float4*)(ap0 + kt * 32 + 4);
        float4 a10 = *(const float4*)(ap1 + kt * 32);
        float4 a11 = *(const float4*)(ap1 + kt * 32 + 4);
        short8 af0, af1;
        af0[0] = (short)bfc(a00.x); af0[1] = (short)bfc(a00.y);
        af0[2] = (short)bfc(a00.z); af0[3] = (short)bfc(a00.w);
        af0[4] = (short)bfc(a01.x); af0[5] = (short)bfc(a01.y);
        af0[6] = (short)bfc(a01.z); af0[7] = (short)bfc(a01.w);
        af1[0] = (short)bfc(a10.x); af1[1] = (short)bfc(a10.y);
        af1[2] = (short)bfc(a10.z); af1[3] = (short)bfc(a10.w);
        af1[4] = (short)bfc(a11.x); af1[5] = (short)bfc(a11.y);
        af1[6] = (short)bfc(a11.z); af1[7] = (short)bfc(a11.w);
#pragma unroll
        for (int nt = 0; nt < 8; ++nt) {
            int n = nt * 16 + lr;
            short8 bf = *(const short8*)((char*)sB +
                        ((n * 1024 + kt * 64 + lq * 16) ^ ((n & 7) << 4)));
            acc[0][nt] = __builtin_amdgcn_mfma_f32_16x16x32_bf16(af0, bf, acc[0][nt], 0, 0, 0);
            acc[1][nt] = __builtin_amdgcn_mfma_f32_16x16x32_bf16(af1, bf, acc[1][nt], 0, 0, 0);
        }
    }

#pragma unroll
    for (int s = 0; s < 2; ++s)
#pragma unroll
        for (int nt = 0; nt < 8; ++nt)
#pragma unroll
            for (int r = 0; r < 4; ++r)
                C[(size_t)(m0 + s * 16 + lq * 4 + r) * FF + nt * 16 + lr] = acc[s][nt][r];
}

// ---------------------------------------------------------------------------
// Layer-2 GEMM (r8 LDS version): Z(pre-swizzled bf16 tiles) @ {Wsv,Wsr2,Wdr2}.
// ---------------------------------------------------------------------------
__global__ void __launch_bounds__(256)
k_gemm_l2(const unsigned short* __restrict__ Zsw, const unsigned short* __restrict__ Bt3,
          float* __restrict__ ACC, unsigned short* __restrict__ SD)
{
    __shared__ __align__(16) unsigned short sA[2][32 * 64];   // 2 x 4 KB
    __shared__ __align__(16) unsigned short sB[2][128 * 64];  // 2 x 16 KB
    const int tid = threadIdx.x, l = tid & 63, w = tid >> 6;
    const int m0 = blockIdx.x * 32;
    const int mat = blockIdx.y, p = blockIdx.z;
    const unsigned short* Zp = Zsw + (size_t)p * 2048000;

    floatx4 acc[2][2];
#pragma unroll
    for (int mt = 0; mt < 2; ++mt)
#pragma unroll
        for (int nt = 0; nt < 2; ++nt) acc[mt][nt] = (floatx4){0.f, 0.f, 0.f, 0.f};

#pragma unroll
    for (int t = 0; t < 2; ++t) {
        const char* bs = (const char*)Bt3 + (size_t)(mat * 2 + t) * 16384 + tid * 16;
#pragma unroll
        for (int q = 0; q < 4; ++q) gload16((char*)sB[t] + tid * 16 + q * 4096, bs + q * 4096);
        gload16((char*)sA[t] + tid * 16,
                (const char*)Zp + (size_t)((m0 >> 5) * 2 + t) * 4096 + tid * 16);
    }
    __syncthreads();

#pragma unroll
    for (int t = 0; t < 2; ++t)
#pragma unroll
        for (int ks = 0; ks < 2; ++ks) {
            short8 ah[2], bh[2];
            const int kb = ks * 64 + (l >> 4) * 16;
#pragma unroll
            for (int mt = 0; mt < 2; ++mt) {
                int row = mt * 16 + (l & 15);
                ah[mt] = *(const short8*)((char*)sA[t] + ((row * 128 + kb) ^ ((row & 7) << 4)));
            }
#pragma unroll
            for (int nt = 0; nt < 2; ++nt) {
                int row = w * 32 + nt * 16 + (l & 15);
                bh[nt] = *(const short8*)((char*)sB[t] + ((row * 128 + kb) ^ ((row & 7) << 4)));
            }
#pragma unroll
            for (int mt = 0; mt < 2; ++mt)
#pragma unroll
                for (int nt = 0; nt < 2; ++nt)
                    acc[mt][nt] = __builtin_amdgcn_mfma_f32_16x16x32_bf16(ah[mt], bh[nt], acc[mt][nt], 0, 0, 0);
        }

    float* ACCp = ACC + (size_t)p * 2048000;
    unsigned short* SDp = (unsigned short*)SD + (size_t)p * 4096000;
#pragma unroll
    for (int mt = 0; mt < 2; ++mt)
#pragma unroll
        for (int nt = 0; nt < 2; ++nt)
#pragma unroll
            for (int r = 0; r < 4; ++r) {
                int row = m0 + mt * 16 + (l >> 4) * 4 + r;
                int col = w * 32 + nt * 16 + (l & 15);
                float v = acc[mt][nt][r];
                if (mat == 0) ACCp[(size_t)row * FF + col] = v;
                else          SDp [(size_t)row * 256 + (mat - 1) * FF + col] = bfc(v);
            }
}

// ---------------------------------------------------------------------------
// Gather 1: Z = relu(ACC + P1 + atoms@Wv + mean(S,sn) + mean(D,dn)) -> Zsw
// (bf16, pre-swizzled tiles for k_gemm_l2's A staging).
// ---------------------------------------------------------------------------
__global__ void __launch_bounds__(256)
k_gather1(const float* __restrict__ ACC, const float* __restrict__ P1,
          const unsigned short* __restrict__ SD,
          const int* __restrict__ sn0, const int* __restrict__ dn0,
          const int* __restrict__ sn1, const int* __restrict__ dn1,
          const float* __restrict__ atoms0, const float* __restrict__ atoms1,
          const float* __restrict__ Wv, unsigned short* __restrict__ Zout)
{
    __shared__ int sIdx[16][20];
    __shared__ float sWv[NCAT * FF];   // 6 KB
    __shared__ float sAt[16 * NCAT];   // 768 B
    const int tid = threadIdx.x;
    const int p = blockIdx.y;
    const int a0 = blockIdx.x * 16;
    const int* sn = p ? sn1 : sn0;
    const int* dn = p ? dn1 : dn0;
    const float* ACCp = ACC + (size_t)p * 2048000;
    const float* P1p  = P1  + (size_t)p * 2048000;
    const unsigned short* SDp = SD + (size_t)p * 4096000;
    unsigned short* Zp = Zout + (size_t)p * 2048000;

    for (int t = tid; t < 320; t += 256) {
        int at = t / 20, q = t - at * 20;
        sIdx[at][q] = (q < 10) ? sn[(a0 + at) * KNN + q] : dn[(a0 + at) * KNN + q - 10];
    }
    {
        const float* atoms = p ? atoms1 : atoms0;
        for (int i = tid; i < 384; i += 256)
            ((float4*)sWv)[i] = ((const float4*)Wv)[i];
        if (tid < 48) {
            int at = tid / 3, q = tid - at * 3;
            *(float4*)&sAt[at * NCAT + q * 4] =
                *(const float4*)&atoms[(size_t)(a0 + at) * NCAT + q * 4];
        }
    }
    __syncthreads();
    const int at = tid >> 4, c8 = tid & 15;
    const int a = a0 + at;
    float ss[8] = {0,0,0,0,0,0,0,0}, dd[8] = {0,0,0,0,0,0,0,0};
    int sc = 0, dc = 0;
#pragma unroll
    for (int n = 0; n < KNN; ++n) {
        int is = sIdx[at][n];
        if (is > -1) {
            sc++;
            uint4 v = *(const uint4*)&SDp[(size_t)is * 256 + c8 * 8];
            uint32_t vv[4] = {v.x, v.y, v.z, v.w};
#pragma unroll
            for (int q = 0; q < 4; ++q) { ss[2*q] += bflo(vv[q]); ss[2*q+1] += bfhi(vv[q]); }
        }
    }
#pragma unroll
    for (int n = 0; n < KNN; ++n) {
        int id = sIdx[at][10 + n];
        if (id > -1) {
            dc++;
            uint4 v = *(const uint4*)&SDp[(size_t)id * 256 + 128 + c8 * 8];
            uint32_t vv[4] = {v.x, v.y, v.z, v.w};
#pragma unroll
            for (int q = 0; q < 4; ++q) { dd[2*q] += bflo(vv[q]); dd[2*q+1] += bfhi(vv[q]); }
        }
    }
    const float rs = 1.f / (sc > 0 ? (float)sc : 1.f);
    const float rd = 1.f / (dc > 0 ? (float)dc : 1.f);
    float4 a0v = *(const float4*)&ACCp[(size_t)a * FF + c8 * 8];
    float4 a1v = *(const float4*)&ACCp[(size_t)a * FF + c8 * 8 + 4];
    float4 p0v = *(const float4*)&P1p[(size_t)a * FF + c8 * 8];
    float4 p1v = *(const float4*)&P1p[(size_t)a * FF + c8 * 8 + 4];
    float ov[8] = {a0v.x + p0v.x, a0v.y + p0v.y, a0v.z + p0v.z, a0v.w + p0v.w,
                   a1v.x + p1v.x, a1v.y + p1v.y, a1v.z + p1v.z, a1v.w + p1v.w};
#pragma unroll
    for (int c = 0; c < NCAT; ++c) {
        float ac = sAt[at * NCAT + c];
        float4 w0 = *(const float4*)&sWv[c * FF + c8 * 8];
        float4 w1 = *(const float4*)&sWv[c * FF + c8 * 8 + 4];
        ov[0] = fmaf(ac, w0.x, ov[0]); ov[1] = fmaf(ac, w0.y, ov[1]);
        ov[2] = fmaf(ac, w0.z, ov[2]); ov[3] = fmaf(ac, w0.w, ov[3]);
        ov[4] = fmaf(ac, w1.x, ov[4]); ov[5] = fmaf(ac, w1.y, ov[5]);
        ov[6] = fmaf(ac, w1.z, ov[6]); ov[7] = fmaf(ac, w1.w, ov[7]);
    }
    ushort8v zv;
#pragma unroll
    for (int e = 0; e < 8; ++e)
        zv[e] = bfc(fmaxf(fmaf(ss[e], rs, fmaf(dd[e], rd, ov[e])), 0.f));
    int ba = ((a >> 5) * 2 + (c8 >> 3)) * 4096
           + (((a & 31) * 128 + (c8 & 7) * 16) ^ ((a & 7) << 4));
    *(ushort8v*)((char*)Zp + ba) = zv;
}

// ---------------------------------------------------------------------------
// Gather 2 fused with residue mean: one block per residue (40 atoms).
// ---------------------------------------------------------------------------
__global__ void __launch_bounds__(256)
k_gather_res(const float* __restrict__ ACC, const unsigned short* __restrict__ SD,
             const int* __restrict__ sn0, const int* __restrict__ dn0,
             const int* __restrict__ sn1, const int* __restrict__ dn1,
             float* __restrict__ R12)
{
    __shared__ int sIdx[APR][20];      // 3.2 KB
    __shared__ float zpart[16][128];   // 8 KB
    const int tid = threadIdx.x;
    const int p = blockIdx.y, r = blockIdx.x;
    const int* sn = p ? sn1 : sn0;
    const int* dn = p ? dn1 : dn0;
    const float* ACCp = ACC + (size_t)p * 2048000;
    const unsigned short* SDp = SD + (size_t)p * 4096000;
    const int aBase = r * APR;

    for (int t = tid; t < APR * 20; t += 256) {
        int at = t / 20, q = t - at * 20;
        sIdx[at][q] = (q < 10) ? sn[(aBase + at) * KNN + q] : dn[(aBase + at) * KNN + q - 10];
    }
    __syncthreads();

    const int at = tid >> 4, c8 = tid & 15;
    float zs[8] = {0,0,0,0,0,0,0,0};
#pragma unroll
    for (int rep = 0; rep < 3; ++rep) {
        int ai = at + rep * 16;
        if (ai < APR) {
            int a = aBase + ai;
            float ss[8] = {0,0,0,0,0,0,0,0}, dd[8] = {0,0,0,0,0,0,0,0};
            int sc = 0, dc = 0;
#pragma unroll
            for (int n = 0; n < KNN; ++n) {
                int is = sIdx[ai][n];
                if (is > -1) {
                    sc++;
                    uint4 v = *(const uint4*)&SDp[(size_t)is * 256 + c8 * 8];
                    uint32_t vv[4] = {v.x, v.y, v.z, v.w};
#pragma unroll
                    for (int q = 0; q < 4; ++q) { ss[2*q] += bflo(vv[q]); ss[2*q+1] += bfhi(vv[q]); }
                }
            }
#pragma unroll
            for (int n = 0; n < KNN; ++n) {
                int id = sIdx[ai][10 + n];
                if (id > -1) {
                    dc++;
                    uint4 v = *(const uint4*)&SDp[(size_t)id * 256 + 128 + c8 * 8];
                    uint32_t vv[4] = {v.x, v.y, v.z, v.w};
#pragma unroll
                    for (int q = 0; q < 4; ++q) { dd[2*q] += bflo(vv[q]); dd[2*q+1] += bfhi(vv[q]); }
                }
            }
            const float rs = 1.f / (sc > 0 ? (float)sc : 1.f);
            const float rd = 1.f / (dc > 0 ? (float)dc : 1.f);
            float4 a0v = *(const float4*)&ACCp[(size_t)a * FF + c8 * 8];
            float4 a1v = *(const float4*)&ACCp[(size_t)a * FF + c8 * 8 + 4];
            float ov[8] = {a0v.x, a0v.y, a0v.z, a0v.w, a1v.x, a1v.y, a1v.z, a1v.w};
#pragma unroll
            for (int e = 0; e < 8; ++e)
                zs[e] += fmaxf(fmaf(ss[e], rs, fmaf(dd[e], rd, ov[e])), 0.f);
        }
    }
    *(float4*)&zpart[at][c8 * 8]     = (float4){zs[0], zs[1], zs[2], zs[3]};
    *(float4*)&zpart[at][c8 * 8 + 4] = (float4){zs[4], zs[5], zs[6], zs[7]};
    __syncthreads();
#pragma unroll
    for (int s = 8; s > 0; s >>= 1) {
        if (at < s) {
            float4 x0 = *(const float4*)&zpart[at + s][c8 * 8];
            float4 x1 = *(const float4*)&zpart[at + s][c8 * 8 + 4];
            float4 y0 = *(const float4*)&zpart[at][c8 * 8];
            float4 y1 = *(const float4*)&zpart[at][c8 * 8 + 4];
            y0.x += x0.x; y0.y += x0.y; y0.z += x0.z; y0.w += x0.w;
            y1.x += x1.x; y1.y += x1.y; y1.z += x1.z; y1.w += x1.w;
            *(float4*)&zpart[at][c8 * 8]     = y0;
            *(float4*)&zpart[at][c8 * 8 + 4] = y1;
        }
        __syncthreads();
    }
    if (at == 0) {
        float* R = R12 + (size_t)p * 51200 + (size_t)r * FF;
        const float inv = 1.0f / APR;
#pragma unroll
        for (int e = 0; e < 8; ++e) R[c8 * 8 + e] = zpart[0][c8 * 8 + e] * inv;
    }
}

// ---------------------------------------------------------------------------
// A1[i] = r1[i] @ Wf1[:128,:] + bf1 ;  B1[j] = r2[j] @ Wf1[128:,:]
// ---------------------------------------------------------------------------
__global__ void k_pairprep(const float* __restrict__ R1, const float* __restrict__ R2,
                           const float* __restrict__ Wf1, const float* __restrict__ bf1,
                           float* __restrict__ A1, float* __restrict__ B1)
{
    __shared__ float r1s[FF], r2s[FF];
    int i = blockIdx.x, o = threadIdx.x;   // 256 threads
    if (o < FF) r1s[o] = R1[i * FF + o];
    else        r2s[o - FF] = R2[i * FF + (o - FF)];
    __syncthreads();
    float sa = bf1[o], sb = 0.f;
#pragma unroll 8
    for (int k = 0; k < FF; ++k) {
        sa = fmaf(r1s[k], Wf1[(size_t)k * DF1 + o], sa);
        sb = fmaf(r2s[k], Wf1[(size_t)(FF + k) * DF1 + o], sb);
    }
    A1[(size_t)i * DF1 + o] = sa;
    B1[(size_t)i * DF1 + o] = sb;
}

// ---------------------------------------------------------------------------
// Pair MLP via MFMA, register-built H.
// ---------------------------------------------------------------------------
__global__ void __launch_bounds__(256)
k_pairs_mfma(const float* __restrict__ A1, const float* __restrict__ B1,
             const unsigned short* __restrict__ W2T,
             const float* __restrict__ bf2, const float* __restrict__ Wf3,
             const float* __restrict__ bf3, float* __restrict__ out)
{
    __shared__ __align__(16) float sA1[16 * 256];            // 16 KB linear
    __shared__ __align__(16) float sB1[16 * 256];            // 16 KB, XOR (row&7)<<5
    __shared__ __align__(16) unsigned short sW[64 * 256];    // 32 KB, XOR (n&7)<<4
    const int tid = threadIdx.x, l = tid & 63, w = tid >> 6;
    const int i0 = blockIdx.x * 16, j0 = blockIdx.y * 16;

    for (int idx = tid; idx < 64 * 32; idx += 256) {
        int row = idx >> 5, c = idx & 31;
        int ba = (row * 512 + c * 16) ^ ((row & 7) << 4);
        *(uint4*)((char*)sW + ba) = *(const uint4*)(W2T + row * 256 + c * 8);
    }
    {
        int row = tid >> 4;
#pragma unroll
        for (int pass = 0; pass < 4; ++pass) {
            int coff = pass * 64 + (tid & 15) * 4;
            *(float4*)((char*)sA1 + row * 1024 + coff * 4) =
                *(const float4*)&A1[(size_t)(i0 + row) * DF1 + coff];
            int bb = (row * 1024 + coff * 4) ^ ((row & 7) << 5);
            *(float4*)((char*)sB1 + bb) =
                *(const float4*)&B1[(size_t)(j0 + row) * DF1 + coff];
        }
    }
    __syncthreads();

    floatx4 acc[4][4];
#pragma unroll
    for (int mt = 0; mt < 4; ++mt)
#pragma unroll
        for (int nt = 0; nt < 4; ++nt) acc[mt][nt] = (floatx4){0.f, 0.f, 0.f, 0.f};

    float b2r[4], w3r[4];
#pragma unroll
    for (int nt = 0; nt < 4; ++nt) {
        b2r[nt] = bf2[nt * 16 + (l & 15)];
        w3r[nt] = Wf3[nt * 16 + (l & 15)];
    }

    const int rB = l & 15, kq = l >> 4;
#pragma unroll
    for (int kc = 0; kc < 4; ++kc)
#pragma unroll
        for (int ks = 0; ks < 2; ++ks) {
            const int kfb = (kc * 64 + ks * 32 + kq * 8) * 4;
            float4 b1a = *(const float4*)((char*)sB1 + ((rB * 1024 + kfb)      ^ ((rB & 7) << 5)));
            float4 b1b = *(const float4*)((char*)sB1 + ((rB * 1024 + kfb + 16) ^ ((rB & 7) << 5)));
            short8 afr[4];
#pragma unroll
            for (int mt = 0; mt < 4; ++mt) {
                int rA = w * 4 + mt;
                float4 a1a = *(const float4*)((char*)sA1 + rA * 1024 + kfb);
                float4 a1b = *(const float4*)((char*)sA1 + rA * 1024 + kfb + 16);
                short8 hv;
                hv[0] = (short)bfc(fmaxf(a1a.x + b1a.x, 0.f));
                hv[1] = (short)bfc(fmaxf(a1a.y + b1a.y, 0.f));
                hv[2] = (short)bfc(fmaxf(a1a.z + b1a.z, 0.f));
                hv[3] = (short)bfc(fmaxf(a1a.w + b1a.w, 0.f));
                hv[4] = (short)bfc(fmaxf(a1b.x + b1b.x, 0.f));
                hv[5] = (short)bfc(fmaxf(a1b.y + b1b.y, 0.f));
                hv[6] = (short)bfc(fmaxf(a1b.z + b1b.z, 0.f));
                hv[7] = (short)bfc(fmaxf(a1b.w + b1b.w, 0.f));
                afr[mt] = hv;
            }
            const int kwb = kc * 128 + ks * 64 + kq * 16;
            short8 bfr[4];
#pragma unroll
            for (int nt = 0; nt < 4; ++nt) {
                int n = nt * 16 + (l & 15);
                bfr[nt] = *(const short8*)((char*)sW + ((n * 512 + kwb) ^ ((n & 7) << 4)));
            }
#pragma unroll
            for (int mt = 0; mt < 4; ++mt)
#pragma unroll
                for (int nt = 0; nt < 4; ++nt)
                    acc[mt][nt] = __builtin_amdgcn_mfma_f32_16x16x32_bf16(afr[mt], bfr[nt], acc[mt][nt], 0, 0, 0);
        }

    const float b3 = bf3[0];
#pragma unroll
    for (int mt = 0; mt < 4; ++mt)
#pragma unroll
        for (int r = 0; r < 4; ++r) {
            float s = 0.f;
#pragma unroll
            for (int nt = 0; nt < 4; ++nt)
                s += fmaxf(acc[mt][nt][r] + b2r[nt], 0.f) * w3r[nt];
            s += __shfl_xor(s, 1); s += __shfl_xor(s, 2);
            s += __shfl_xor(s, 4); s += __shfl_xor(s, 8);
            if ((l & 15) == 0) {
                int p = w * 64 + mt * 16 + (l >> 4) * 4 + r;
                out[(size_t)(i0 + (p >> 4)) * NRES + j0 + (p & 15)] = s + b3;
            }
        }
}

// ---------------------------------------------------------------------------
extern "C" void kernel_launch(void* const* d_in, const int* in_sizes, int n_in,
                              void* d_out, int out_size, void* d_ws, size_t ws_size,
                              hipStream_t stream)
{
    const float* atoms0    = (const float*)d_in[0];
    const float* residues0 = (const float*)d_in[1];
    const int*   same0     = (const int*)d_in[2];
    const int*   diff0     = (const int*)d_in[3];
    const float* atoms1    = (const float*)d_in[5];
    const float* residues1 = (const float*)d_in[6];
    const int*   same1     = (const int*)d_in[7];
    const int*   diff1     = (const int*)d_in[8];
    const float* Wv   = (const float*)d_in[10];
    const float* Wr   = (const float*)d_in[11];
    const float* Wsr1 = (const float*)d_in[12];
    const float* Wdr1 = (const float*)d_in[13];
    const float* Wsv  = (const float*)d_in[14];
    const float* Wsr2 = (const float*)d_in[15];
    const float* Wdr2 = (const float*)d_in[16];
    const float* Wf1  = (const float*)d_in[17];
    const float* bf1  = (const float*)d_in[18];
    const float* Wf2  = (const float*)d_in[19];
    const float* bf2  = (const float*)d_in[20];
    const float* Wf3  = (const float*)d_in[21];
    const float* bf3  = (const float*)d_in[22];

    float* ws  = (float*)d_ws;
    float* ACC = ws;                                         // 2 x 2,048,000 f
    float* P1  = ws + 4096000;                               // 2 x 2,048,000 f
    unsigned short* SD  = (unsigned short*)(ws + 8192000);   // 2 x 4,096,000 u16
    unsigned short* Zsw = (unsigned short*)(ws + 12288000);  // 2 x 2,048,000 u16
    float* R12 = ws + 14336000;                              // 2 x 51,200 f
    float* A1  = ws + 14438400;                              // 102,400 f
    float* B1  = ws + 14540800;                              // 102,400 f
    unsigned short* WrT = (unsigned short*)(ws + 14643200);  // 131,072 u16
    unsigned short* Bt3 = (unsigned short*)(ws + 14708736);  //  49,152 u16
    unsigned short* W2T = (unsigned short*)(ws + 14733312);  //  16,384 u16

    k_prep<<<152, 256, 0, stream>>>(Wr, Wsv, Wsr2, Wdr2, Wf2, WrT, Bt3, W2T);
    k_atomsSD<<<dim3(NA / 64, 2), 256, 0, stream>>>(atoms0, atoms1, Wsr1, Wdr1, SD);
    k_gemm_big<<<dim3(63, 2, 2), 512, 0, stream>>>(residues0, residues1, WrT, ACC, P1);
    k_gather1<<<dim3(NA / 16, 2), 256, 0, stream>>>(ACC, P1, SD, same0, diff0, same1, diff1,
                                                    atoms0, atoms1, Wv, Zsw);
    k_gemm_l2<<<dim3(NA / 32, 3, 2), 256, 0, stream>>>(Zsw, Bt3, ACC, SD);
    k_gather_res<<<dim3(NRES, 2), 256, 0, stream>>>(ACC, SD, same0, diff0, same1, diff1, R12);
    k_pairprep<<<NRES, 256, 0, stream>>>(R12, R12 + 51200, Wf1, bf1, A1, B1);
    k_pairs_mfma<<<dim3(25, 25), 256, 0, stream>>>(A1, B1, W2T, bf2, Wf3, bf3, (float*)d_out);
}